// Round 8
// baseline (3967.984 us; speedup 1.0000x reference)
//
#include <hip/hip_runtime.h>

typedef __bf16 bf16_t;
typedef __attribute__((ext_vector_type(8))) __bf16 bf16x8;
typedef __attribute__((ext_vector_type(4))) float f32x4;
typedef __attribute__((ext_vector_type(4))) unsigned int u32x4;

#define NSEQ 1024
#define SLEN 100
#define HID  512

__device__ __forceinline__ float sigf(float x) { return 1.0f / (1.0f + __expf(-x)); }
__device__ __forceinline__ float tanh_(float x) { return 1.0f - 2.0f / (__expf(2.0f * x) + 1.0f); }

__device__ __forceinline__ bf16x8 cvt8(float4 a, float4 b) {
    bf16x8 v;
    v[0] = (__bf16)a.x; v[1] = (__bf16)a.y; v[2] = (__bf16)a.z; v[3] = (__bf16)a.w;
    v[4] = (__bf16)b.x; v[5] = (__bf16)b.y; v[6] = (__bf16)b.z; v[7] = (__bf16)b.w;
    return v;
}

// ---------------------------------------------------------------------------
// Embedding GEMM: emb[t][seq][h] = sum_d x[seq][t][d] * W_e[h][d] + b_e[h]
// ---------------------------------------------------------------------------
__global__ __launch_bounds__(256)
void embed_kernel(const float* __restrict__ x, const float* __restrict__ We,
                  const float* __restrict__ be, bf16_t* __restrict__ emb)
{
    __shared__ bf16_t bsm[8 * 256 * 8];   // [q=k/8][col][8] bf16 = 32 KB
    const int bid = blockIdx.x;
    const int rowblk = bid >> 1;
    const int col0 = (bid & 1) << 8;
    const int tid = threadIdx.x;

    {
        const int col = tid;  // 0..255
        const float* src = We + (size_t)(col0 + col) * 64;
        #pragma unroll
        for (int q = 0; q < 8; ++q) {
            float4 f0 = *(const float4*)(src + q * 8);
            float4 f1 = *(const float4*)(src + q * 8 + 4);
            *(bf16x8*)&bsm[(q * 256 + col) * 8] = cvt8(f0, f1);
        }
    }
    __syncthreads();

    const int l = tid & 63, w = tid >> 6;
    const int lo = l & 15, hi = l >> 4;
    const int rowbase = rowblk * 64 + w * 16;
    const int row_a = rowbase + lo;
    const int seq = row_a & (NSEQ - 1);
    const int t = row_a >> 10;
    const float* xrow = x + ((size_t)seq * SLEN + t) * 64;

    bf16x8 a0, a1;
    {
        const float* p = xrow + hi * 8;
        a0 = cvt8(*(const float4*)p, *(const float4*)(p + 4));
        p = xrow + 32 + hi * 8;
        a1 = cvt8(*(const float4*)p, *(const float4*)(p + 4));
    }

    #pragma unroll
    for (int nf = 0; nf < 16; ++nf) {
        f32x4 acc = {0.f, 0.f, 0.f, 0.f};
        bf16x8 b0 = *(const bf16x8*)&bsm[((0 * 4 + hi) * 256 + nf * 16 + lo) * 8];
        bf16x8 b1 = *(const bf16x8*)&bsm[((1 * 4 + hi) * 256 + nf * 16 + lo) * 8];
        acc = __builtin_amdgcn_mfma_f32_16x16x32_bf16(a0, b0, acc, 0, 0, 0);
        acc = __builtin_amdgcn_mfma_f32_16x16x32_bf16(a1, b1, acc, 0, 0, 0);
        const int col = col0 + nf * 16 + lo;
        const float bias = be[col];
        #pragma unroll
        for (int r = 0; r < 4; ++r) {
            const int rr = rowbase + hi * 4 + r;
            emb[(size_t)rr * HID + col] = (bf16_t)(acc[r] + bias);
        }
    }
}

// ---------------------------------------------------------------------------
// Persistent masked-LSTM. 256 blocks x 512 threads, 128 KB LDS, 1 block/CU.
// Group m = bid&7 (32 blocks = 256 waves). PER-WAVE sync: the group counter
// counts wave arrivals (256/step); no __syncthreads inside the t-loop, so
// waves slide out of phase and one wave's MFMA/LDS overlaps another's cell
// VALU / spin / stores. Fast path (group XCD-local, verified via
// HW_REG_XCC_ID): h exchanged via L1-bypass (sc0) loads through the shared
// per-XCD L2 — no per-step L2 invalidate/writeback. Agent-scope fallback.
// Wave = 16 seqs x 64 gate-cols (4 N-frags = i,f,g,o at 16 units); cell
// update fully lane-local; weights LDS-resident (read-only after staging).
// ---------------------------------------------------------------------------
__global__ __launch_bounds__(512, 2)
void lstm_kernel(const bf16_t* __restrict__ emb, const int* __restrict__ mask,
                 const float* __restrict__ Wih, const float* __restrict__ Whh,
                 const float* __restrict__ bih, const float* __restrict__ bhh,
                 const float* __restrict__ h0, const float* __restrict__ c0,
                 bf16_t* __restrict__ hbuf,        // [2][1024][512] bf16
                 unsigned int* __restrict__ cnt,   // [0..511] counters, [512..519] xcd masks
                 float* __restrict__ out)
{
    extern __shared__ bf16_t wsm[];   // [q=k/8 (128)][col (64)][8] = 128 KB
    const int bid = blockIdx.x;
    const int m = bid & 7;            // group (XCD-local with round-robin dispatch)
    const int jsl = bid >> 3;         // 0..31
    const int jbase = jsl * 16;       // 16 hidden units per block
    const int tid = threadIdx.x;

    // publish this block's XCD id into the group's mask (before init arrival)
    unsigned xcc = 0;
    asm volatile("s_getreg_b32 %0, hwreg(HW_REG_XCC_ID)" : "=s"(xcc));
    if (tid == 0)
        __hip_atomic_fetch_or(&cnt[512 + m], 1u << (xcc & 31u),
                              __ATOMIC_RELAXED, __HIP_MEMORY_SCOPE_AGENT);

    // ---- stage weight slice: wsm[q][col][e] = Wcat[G(col)][q*8+e] ----
    {
        const int col = tid & 63;
        const int qg = tid >> 6;          // 0..7
        const int grp = col >> 4;
        const int jj = col & 15;
        const int G = grp * 512 + jbase + jj;
        #pragma unroll
        for (int i = 0; i < 16; ++i) {
            const int q = qg * 16 + i;    // 0..127
            const int k0 = q * 8;
            const float* src = (k0 < 512) ? (Wih + (size_t)G * 512 + k0)
                                          : (Whh + (size_t)G * 512 + (k0 - 512));
            float4 f0 = *(const float4*)src;
            float4 f1 = *(const float4*)(src + 4);
            *(bf16x8*)&wsm[(q * 64 + col) * 8] = cvt8(f0, f1);
        }
    }

    const int lane = tid & 63, w = tid >> 6;
    const int lo = lane & 15, hi = lane >> 4;
    const int seqbase = m * 128 + w * 16;
    const int jg = jbase + lo;
    const int seq_a = seqbase + lo;       // this lane's A row
    const int koff = hi * 8;

    float bs[4];
    #pragma unroll
    for (int g = 0; g < 4; ++g) bs[g] = bih[g * 512 + jg] + bhh[g * 512 + jg];

    // init c and h(0) = mask0 ? emb0 : h0  (per-wave: covers 16 seqs x 16 units)
    float c_reg[4];
    const float c0v = c0[jg], h0v = h0[jg];
    #pragma unroll
    for (int r = 0; r < 4; ++r) {
        const int seq = seqbase + hi * 4 + r;
        c_reg[r] = c0v;
        const int mb0 = mask[(size_t)seq * SLEN + 0];
        const float e0 = (float)emb[(size_t)seq * HID + jg];
        hbuf[(size_t)seq * HID + jg] = (bf16_t)(mb0 ? e0 : h0v);
    }
    // LDS staging visible to all waves of this block before the t-loop
    __syncthreads();
    // per-wave init arrival (release: cross-XCD-safe at init)
    asm volatile("s_waitcnt vmcnt(0)" ::: "memory");
    if ((tid & 63) == 0)
        __hip_atomic_fetch_add(&cnt[m * 64], 1u, __ATOMIC_RELEASE,
                               __HIP_MEMORY_SCOPE_AGENT);

    bool fast = false;

    for (int t = 0; t < SLEN; ++t) {
        // ---- prefetch (h-independent) before the spin: mask + emb frags ----
        const int mb = mask[(size_t)seq_a * SLEN + t];
        const bf16_t* erow = emb + ((size_t)t * NSEQ + seq_a) * HID + koff;
        bf16x8 ex[16];
        #pragma unroll
        for (int kt = 0; kt < 16; ++kt)
            ex[kt] = *(const bf16x8*)(erow + kt * 32);

        // ---- per-wave group spin: wait for all 256 waves of group m ----
        {
            const unsigned target = 256u * (unsigned)(t + 1);
            unsigned it = 0;
            while (__hip_atomic_load(&cnt[m * 64], __ATOMIC_RELAXED,
                                     __HIP_MEMORY_SCOPE_AGENT) < target &&
                   ++it < (1u << 27)) {
                __builtin_amdgcn_s_sleep(1);
            }
            if (!fast)   // slow path: agent acquire (L2 invalidate)
                (void)__hip_atomic_load(&cnt[m * 64], __ATOMIC_ACQUIRE,
                                        __HIP_MEMORY_SCOPE_AGENT);
        }
        if (t == 0) {
            const unsigned gm = __hip_atomic_load(&cnt[512 + m], __ATOMIC_RELAXED,
                                                  __HIP_MEMORY_SCOPE_AGENT);
            fast = (__popc(gm) == 1);   // uniform across the group's waves
        }

        const bf16_t* hb_r = hbuf + (size_t)(t & 1) * (NSEQ * HID);
        bf16_t* hb_w = hbuf + (size_t)((t + 1) & 1) * (NSEQ * HID);
        const unsigned long long hrow =
            (unsigned long long)(hb_r + (size_t)seq_a * HID + koff);

        // ---- forced h prefetch: L1-bypass (sc0) loads, L2-hit in fast path ----
        union HU { u32x4 u; bf16x8 h; };
        HU h_[16];
        #define HL(i, OFF) \
            asm volatile("global_load_dwordx4 %0, %1, off offset:" OFF " sc0" \
                         : "=v"(h_[i].u) : "v"(hrow));
        HL(0, "0")    HL(1, "64")   HL(2, "128")  HL(3, "192")
        HL(4, "256")  HL(5, "320")  HL(6, "384")  HL(7, "448")
        HL(8, "512")  HL(9, "576")  HL(10, "640") HL(11, "704")
        HL(12, "768") HL(13, "832") HL(14, "896") HL(15, "960")
        #undef HL
        asm volatile("s_waitcnt vmcnt(0)" ::: "memory");
        __builtin_amdgcn_sched_barrier(0);

        f32x4 acc[4];
        #pragma unroll
        for (int nf = 0; nf < 4; ++nf) acc[nf] = (f32x4){0.f, 0.f, 0.f, 0.f};

        // K = [0,512): xt = select(mask, emb, h)
        #pragma unroll
        for (int kt = 0; kt < 16; ++kt) {
            const bf16x8 a = mb ? ex[kt] : h_[kt].h;
            #pragma unroll
            for (int nf = 0; nf < 4; ++nf) {
                const bf16x8 b =
                    *(const bf16x8*)&wsm[((kt * 4 + hi) * 64 + nf * 16 + lo) * 8];
                acc[nf] = __builtin_amdgcn_mfma_f32_16x16x32_bf16(a, b, acc[nf], 0, 0, 0);
            }
        }
        // K = [512,1024): h
        #pragma unroll
        for (int kt = 0; kt < 16; ++kt) {
            #pragma unroll
            for (int nf = 0; nf < 4; ++nf) {
                const bf16x8 b =
                    *(const bf16x8*)&wsm[(((kt + 16) * 4 + hi) * 64 + nf * 16 + lo) * 8];
                acc[nf] = __builtin_amdgcn_mfma_f32_16x16x32_bf16(h_[kt].h, b, acc[nf], 0, 0, 0);
            }
        }

        // ---- lane-local LSTM cell update (acc[0..3] = i,f,g,o at unit jg) ----
        #pragma unroll
        for (int r = 0; r < 4; ++r) {
            const float iv = acc[0][r] + bs[0];
            const float fv = acc[1][r] + bs[1];
            const float gv = acc[2][r] + bs[2];
            const float ov = acc[3][r] + bs[3];
            const float cn = sigf(fv) * c_reg[r] + sigf(iv) * tanh_(gv);
            c_reg[r] = cn;
            const float hv = sigf(ov) * tanh_(cn);
            const int s = seqbase + hi * 4 + r;
            hb_w[(size_t)s * HID + jg] = (bf16_t)hv;
            if (t == SLEN - 1) out[(size_t)s * HID + jg] = hv;
        }

        // ---- per-wave arrival: stores drained, then one add per wave ----
        asm volatile("s_waitcnt vmcnt(0)" ::: "memory");
        if ((tid & 63) == 0) {
            if (fast)
                __hip_atomic_fetch_add(&cnt[m * 64], 1u, __ATOMIC_RELAXED,
                                       __HIP_MEMORY_SCOPE_AGENT);
            else
                __hip_atomic_fetch_add(&cnt[m * 64], 1u, __ATOMIC_RELEASE,
                                       __HIP_MEMORY_SCOPE_AGENT);
        }
    }
}

// ---------------------------------------------------------------------------
extern "C" void kernel_launch(void* const* d_in, const int* in_sizes, int n_in,
                              void* d_out, int out_size, void* d_ws, size_t ws_size,
                              hipStream_t stream)
{
    const float* x    = (const float*)d_in[0];
    const int*   mask = (const int*)d_in[1];
    const float* We   = (const float*)d_in[2];
    const float* be   = (const float*)d_in[3];
    const float* Wih  = (const float*)d_in[4];
    const float* Whh  = (const float*)d_in[5];
    const float* bih  = (const float*)d_in[6];
    const float* bhh  = (const float*)d_in[7];
    const float* h0   = (const float*)d_in[8];
    const float* c0   = (const float*)d_in[9];
    float* out = (float*)d_out;

    unsigned char* ws = (unsigned char*)d_ws;
    unsigned int* cnt = (unsigned int*)ws;                       // 4 KB
    bf16_t* hbuf = (bf16_t*)(ws + 4096);                         // 2 MB
    bf16_t* emb  = (bf16_t*)(ws + 4096 + (size_t)2 * NSEQ * HID * 2);  // ~100 MB

    hipMemsetAsync(cnt, 0, 4096, stream);

    embed_kernel<<<3200, 256, 0, stream>>>(x, We, be, emb);

    hipFuncSetAttribute(reinterpret_cast<const void*>(lstm_kernel),
                        hipFuncAttributeMaxDynamicSharedMemorySize, 131072);
    lstm_kernel<<<256, 512, 131072, stream>>>(emb, mask, Wih, Whh, bih, bhh,
                                              h0, c0, hbuf, cnt, out);
}

// Round 9
// 1682.333 us; speedup vs baseline: 2.3586x; 2.3586x over previous
//
#include <hip/hip_runtime.h>

typedef __bf16 bf16_t;
typedef __attribute__((ext_vector_type(8))) __bf16 bf16x8;
typedef __attribute__((ext_vector_type(4))) float f32x4;
typedef __attribute__((ext_vector_type(4))) unsigned int u32x4;

#define NSEQ 1024
#define SLEN 100
#define HID  512

__device__ __forceinline__ float sigf(float x) { return 1.0f / (1.0f + __expf(-x)); }
__device__ __forceinline__ float tanh_(float x) { return 1.0f - 2.0f / (__expf(2.0f * x) + 1.0f); }

__device__ __forceinline__ bf16x8 cvt8(float4 a, float4 b) {
    bf16x8 v;
    v[0] = (__bf16)a.x; v[1] = (__bf16)a.y; v[2] = (__bf16)a.z; v[3] = (__bf16)a.w;
    v[4] = (__bf16)b.x; v[5] = (__bf16)b.y; v[6] = (__bf16)b.z; v[7] = (__bf16)b.w;
    return v;
}

// ---------------------------------------------------------------------------
// Embedding GEMM: emb[t][seq][h] = sum_d x[seq][t][d] * W_e[h][d] + b_e[h]
// ---------------------------------------------------------------------------
__global__ __launch_bounds__(256)
void embed_kernel(const float* __restrict__ x, const float* __restrict__ We,
                  const float* __restrict__ be, bf16_t* __restrict__ emb)
{
    __shared__ bf16_t bsm[8 * 256 * 8];   // [q=k/8][col][8] bf16 = 32 KB
    const int bid = blockIdx.x;
    const int rowblk = bid >> 1;
    const int col0 = (bid & 1) << 8;
    const int tid = threadIdx.x;

    {
        const int col = tid;  // 0..255
        const float* src = We + (size_t)(col0 + col) * 64;
        #pragma unroll
        for (int q = 0; q < 8; ++q) {
            float4 f0 = *(const float4*)(src + q * 8);
            float4 f1 = *(const float4*)(src + q * 8 + 4);
            *(bf16x8*)&bsm[(q * 256 + col) * 8] = cvt8(f0, f1);
        }
    }
    __syncthreads();

    const int l = tid & 63, w = tid >> 6;
    const int lo = l & 15, hi = l >> 4;
    const int rowbase = rowblk * 64 + w * 16;
    const int row_a = rowbase + lo;
    const int seq = row_a & (NSEQ - 1);
    const int t = row_a >> 10;
    const float* xrow = x + ((size_t)seq * SLEN + t) * 64;

    bf16x8 a0, a1;
    {
        const float* p = xrow + hi * 8;
        a0 = cvt8(*(const float4*)p, *(const float4*)(p + 4));
        p = xrow + 32 + hi * 8;
        a1 = cvt8(*(const float4*)p, *(const float4*)(p + 4));
    }

    #pragma unroll
    for (int nf = 0; nf < 16; ++nf) {
        f32x4 acc = {0.f, 0.f, 0.f, 0.f};
        bf16x8 b0 = *(const bf16x8*)&bsm[((0 * 4 + hi) * 256 + nf * 16 + lo) * 8];
        bf16x8 b1 = *(const bf16x8*)&bsm[((1 * 4 + hi) * 256 + nf * 16 + lo) * 8];
        acc = __builtin_amdgcn_mfma_f32_16x16x32_bf16(a0, b0, acc, 0, 0, 0);
        acc = __builtin_amdgcn_mfma_f32_16x16x32_bf16(a1, b1, acc, 0, 0, 0);
        const int col = col0 + nf * 16 + lo;
        const float bias = be[col];
        #pragma unroll
        for (int r = 0; r < 4; ++r) {
            const int rr = rowbase + hi * 4 + r;
            emb[(size_t)rr * HID + col] = (bf16_t)(acc[r] + bias);
        }
    }
}

// ---------------------------------------------------------------------------
// Persistent masked-LSTM. 256 blocks x 512 threads, 128 KB LDS, 1 block/CU.
// Group m = bid&7 (32 blocks, XCD-local). Wave w (= seq-group sg) owns 16
// seqs x 16 units. KEY: wave (b, sg) reads h rows of its 16 seqs only, which
// are written by the sg-partner waves of the group's 32 blocks. So sync is a
// per-(m,sg) counter: 32 arrivals + 32 spinners per counter per step (R7's
// proven rate), and the 8 sg pipelines per group drift independently — NO
// __syncthreads in the t-loop (weights LDS read-only; nothing block-shared).
// Fast path (group XCD-local via HW_REG_XCC_ID): h via L1-bypass (sc0) loads
// through the shared per-XCD L2, relaxed arrival — no per-step L2
// invalidate/writeback. Agent-scope fallback otherwise.
// ---------------------------------------------------------------------------
__global__ __launch_bounds__(512, 2)
void lstm_kernel(const bf16_t* __restrict__ emb, const int* __restrict__ mask,
                 const float* __restrict__ Wih, const float* __restrict__ Whh,
                 const float* __restrict__ bih, const float* __restrict__ bhh,
                 const float* __restrict__ h0, const float* __restrict__ c0,
                 bf16_t* __restrict__ hbuf,        // [2][1024][512] bf16
                 unsigned int* __restrict__ cnt,   // [(m*8+sg)*64] counters; [4096+m] xcd masks
                 float* __restrict__ out)
{
    extern __shared__ bf16_t wsm[];   // [q=k/8 (128)][col (64)][8] = 128 KB
    const int bid = blockIdx.x;
    const int m = bid & 7;            // group (XCD-local with round-robin dispatch)
    const int jsl = bid >> 3;         // 0..31
    const int jbase = jsl * 16;       // 16 hidden units per block
    const int tid = threadIdx.x;

    // publish this block's XCD id into the group's mask (before init arrival)
    unsigned xcc = 0;
    asm volatile("s_getreg_b32 %0, hwreg(HW_REG_XCC_ID)" : "=s"(xcc));
    if (tid == 0)
        __hip_atomic_fetch_or(&cnt[4096 + m], 1u << (xcc & 31u),
                              __ATOMIC_RELAXED, __HIP_MEMORY_SCOPE_AGENT);

    // ---- stage weight slice: wsm[q][col][e] = Wcat[G(col)][q*8+e] ----
    {
        const int col = tid & 63;
        const int qg = tid >> 6;          // 0..7
        const int grp = col >> 4;
        const int jj = col & 15;
        const int G = grp * 512 + jbase + jj;
        #pragma unroll
        for (int i = 0; i < 16; ++i) {
            const int q = qg * 16 + i;    // 0..127
            const int k0 = q * 8;
            const float* src = (k0 < 512) ? (Wih + (size_t)G * 512 + k0)
                                          : (Whh + (size_t)G * 512 + (k0 - 512));
            float4 f0 = *(const float4*)src;
            float4 f1 = *(const float4*)(src + 4);
            *(bf16x8*)&wsm[(q * 64 + col) * 8] = cvt8(f0, f1);
        }
    }

    const int lane = tid & 63, w = tid >> 6;   // w = sg (0..7)
    const int lo = lane & 15, hi = lane >> 4;
    const int seqbase = m * 128 + w * 16;
    const int jg = jbase + lo;
    const int seq_a = seqbase + lo;       // this lane's A row
    const int koff = hi * 8;
    unsigned int* const myc = &cnt[(m * 8 + w) * 64];   // this sg's counter

    float bs[4];
    #pragma unroll
    for (int g = 0; g < 4; ++g) bs[g] = bih[g * 512 + jg] + bhh[g * 512 + jg];

    // init c and h(0) = mask0 ? emb0 : h0  (wave covers its 16 seqs x 16 units)
    float c_reg[4];
    const float c0v = c0[jg], h0v = h0[jg];
    #pragma unroll
    for (int r = 0; r < 4; ++r) {
        const int seq = seqbase + hi * 4 + r;
        c_reg[r] = c0v;
        const int mb0 = mask[(size_t)seq * SLEN + 0];
        const float e0 = (float)emb[(size_t)seq * HID + jg];
        hbuf[(size_t)seq * HID + jg] = (bf16_t)(mb0 ? e0 : h0v);
    }
    // LDS staging visible to all waves of this block before the t-loop
    __syncthreads();
    // per-wave init arrival for this sg (release: cross-XCD-safe at init)
    asm volatile("s_waitcnt vmcnt(0)" ::: "memory");
    if (lane == 0)
        __hip_atomic_fetch_add(myc, 1u, __ATOMIC_RELEASE,
                               __HIP_MEMORY_SCOPE_AGENT);

    bool fast = false;

    for (int t = 0; t < SLEN; ++t) {
        // ---- prefetch (h-independent) BEFORE the spin: mask + emb frags.
        //      asm volatile so they cannot be sunk below the spin. ----
        const int mb = mask[(size_t)seq_a * SLEN + t];
        const unsigned long long erow =
            (unsigned long long)(emb + ((size_t)t * NSEQ + seq_a) * HID + koff);
        union HU { u32x4 u; bf16x8 h; };
        HU e_[16];
        #define EL(i, OFF) \
            asm volatile("global_load_dwordx4 %0, %1, off offset:" OFF \
                         : "=v"(e_[i].u) : "v"(erow));
        EL(0, "0")    EL(1, "64")   EL(2, "128")  EL(3, "192")
        EL(4, "256")  EL(5, "320")  EL(6, "384")  EL(7, "448")
        EL(8, "512")  EL(9, "576")  EL(10, "640") EL(11, "704")
        EL(12, "768") EL(13, "832") EL(14, "896") EL(15, "960")
        #undef EL

        // ---- per-sg spin: wait for the 32 sg-partner waves (lane 0 only) ----
        {
            const unsigned target = 32u * (unsigned)(t + 1);
            if (lane == 0) {
                unsigned it = 0;
                while (__hip_atomic_load(myc, __ATOMIC_RELAXED,
                                         __HIP_MEMORY_SCOPE_AGENT) < target &&
                       ++it < (1u << 27)) {
                    __builtin_amdgcn_s_sleep(1);
                }
                if (!fast)   // slow path: agent acquire (L2 invalidate)
                    (void)__hip_atomic_load(myc, __ATOMIC_ACQUIRE,
                                            __HIP_MEMORY_SCOPE_AGENT);
            }
        }
        if (t == 0) {
            const unsigned gm = __hip_atomic_load(&cnt[4096 + m], __ATOMIC_RELAXED,
                                                  __HIP_MEMORY_SCOPE_AGENT);
            fast = (__popc(gm) == 1);   // uniform across the group's waves
        }

        const bf16_t* hb_r = hbuf + (size_t)(t & 1) * (NSEQ * HID);
        bf16_t* hb_w = hbuf + (size_t)((t + 1) & 1) * (NSEQ * HID);
        const unsigned long long hrow =
            (unsigned long long)(hb_r + (size_t)seq_a * HID + koff);

        // ---- forced h prefetch: L1-bypass (sc0) loads, L2-hit in fast path ----
        HU h_[16];
        #define HL(i, OFF) \
            asm volatile("global_load_dwordx4 %0, %1, off offset:" OFF " sc0" \
                         : "=v"(h_[i].u) : "v"(hrow));
        HL(0, "0")    HL(1, "64")   HL(2, "128")  HL(3, "192")
        HL(4, "256")  HL(5, "320")  HL(6, "384")  HL(7, "448")
        HL(8, "512")  HL(9, "576")  HL(10, "640") HL(11, "704")
        HL(12, "768") HL(13, "832") HL(14, "896") HL(15, "960")
        #undef HL
        asm volatile("s_waitcnt vmcnt(0)" ::: "memory");
        __builtin_amdgcn_sched_barrier(0);

        f32x4 acc[4];
        #pragma unroll
        for (int nf = 0; nf < 4; ++nf) acc[nf] = (f32x4){0.f, 0.f, 0.f, 0.f};

        // K = [0,512): xt = select(mask, emb, h)
        #pragma unroll
        for (int kt = 0; kt < 16; ++kt) {
            const bf16x8 a = mb ? e_[kt].h : h_[kt].h;
            #pragma unroll
            for (int nf = 0; nf < 4; ++nf) {
                const bf16x8 b =
                    *(const bf16x8*)&wsm[((kt * 4 + hi) * 64 + nf * 16 + lo) * 8];
                acc[nf] = __builtin_amdgcn_mfma_f32_16x16x32_bf16(a, b, acc[nf], 0, 0, 0);
            }
        }
        // K = [512,1024): h
        #pragma unroll
        for (int kt = 0; kt < 16; ++kt) {
            #pragma unroll
            for (int nf = 0; nf < 4; ++nf) {
                const bf16x8 b =
                    *(const bf16x8*)&wsm[(((kt + 16) * 4 + hi) * 64 + nf * 16 + lo) * 8];
                acc[nf] = __builtin_amdgcn_mfma_f32_16x16x32_bf16(h_[kt].h, b, acc[nf], 0, 0, 0);
            }
        }

        // ---- lane-local LSTM cell update (acc[0..3] = i,f,g,o at unit jg) ----
        #pragma unroll
        for (int r = 0; r < 4; ++r) {
            const float iv = acc[0][r] + bs[0];
            const float fv = acc[1][r] + bs[1];
            const float gv = acc[2][r] + bs[2];
            const float ov = acc[3][r] + bs[3];
            const float cn = sigf(fv) * c_reg[r] + sigf(iv) * tanh_(gv);
            c_reg[r] = cn;
            const float hv = sigf(ov) * tanh_(cn);
            const int s = seqbase + hi * 4 + r;
            hb_w[(size_t)s * HID + jg] = (bf16_t)hv;
            if (t == SLEN - 1) out[(size_t)s * HID + jg] = hv;
        }

        // ---- per-wave arrival: wave's loads+stores drained, then one add ----
        asm volatile("s_waitcnt vmcnt(0)" ::: "memory");
        if (lane == 0) {
            if (fast)
                __hip_atomic_fetch_add(myc, 1u, __ATOMIC_RELAXED,
                                       __HIP_MEMORY_SCOPE_AGENT);
            else
                __hip_atomic_fetch_add(myc, 1u, __ATOMIC_RELEASE,
                                       __HIP_MEMORY_SCOPE_AGENT);
        }
    }
}

// ---------------------------------------------------------------------------
extern "C" void kernel_launch(void* const* d_in, const int* in_sizes, int n_in,
                              void* d_out, int out_size, void* d_ws, size_t ws_size,
                              hipStream_t stream)
{
    const float* x    = (const float*)d_in[0];
    const int*   mask = (const int*)d_in[1];
    const float* We   = (const float*)d_in[2];
    const float* be   = (const float*)d_in[3];
    const float* Wih  = (const float*)d_in[4];
    const float* Whh  = (const float*)d_in[5];
    const float* bih  = (const float*)d_in[6];
    const float* bhh  = (const float*)d_in[7];
    const float* h0   = (const float*)d_in[8];
    const float* c0   = (const float*)d_in[9];
    float* out = (float*)d_out;

    unsigned char* ws = (unsigned char*)d_ws;
    unsigned int* cnt = (unsigned int*)ws;                       // 32 KB (64 counters @256B + masks)
    bf16_t* hbuf = (bf16_t*)(ws + 32768);                        // 2 MB
    bf16_t* emb  = (bf16_t*)(ws + 32768 + (size_t)2 * NSEQ * HID * 2);  // ~100 MB

    hipMemsetAsync(cnt, 0, 32768, stream);

    embed_kernel<<<3200, 256, 0, stream>>>(x, We, be, emb);

    hipFuncSetAttribute(reinterpret_cast<const void*>(lstm_kernel),
                        hipFuncAttributeMaxDynamicSharedMemorySize, 131072);
    lstm_kernel<<<256, 512, 131072, stream>>>(emb, mask, Wih, Whh, bih, bhh,
                                              h0, c0, hbuf, cnt, out);
}

// Round 10
// 1105.108 us; speedup vs baseline: 3.5906x; 1.5223x over previous
//
#include <hip/hip_runtime.h>

typedef __bf16 bf16_t;
typedef __attribute__((ext_vector_type(8))) __bf16 bf16x8;
typedef __attribute__((ext_vector_type(4))) float f32x4;
typedef __attribute__((ext_vector_type(4))) unsigned int u32x4;

#define NSEQ 1024
#define SLEN 100
#define HID  512

__device__ __forceinline__ float sigf(float x) { return 1.0f / (1.0f + __expf(-x)); }
__device__ __forceinline__ float tanh_(float x) { return 1.0f - 2.0f / (__expf(2.0f * x) + 1.0f); }

__device__ __forceinline__ bf16x8 cvt8(float4 a, float4 b) {
    bf16x8 v;
    v[0] = (__bf16)a.x; v[1] = (__bf16)a.y; v[2] = (__bf16)a.z; v[3] = (__bf16)a.w;
    v[4] = (__bf16)b.x; v[5] = (__bf16)b.y; v[6] = (__bf16)b.z; v[7] = (__bf16)b.w;
    return v;
}

// ---------------------------------------------------------------------------
// Embedding GEMM: emb[t][seq][h] = sum_d x[seq][t][d] * W_e[h][d] + b_e[h]
// ---------------------------------------------------------------------------
__global__ __launch_bounds__(256)
void embed_kernel(const float* __restrict__ x, const float* __restrict__ We,
                  const float* __restrict__ be, bf16_t* __restrict__ emb)
{
    __shared__ bf16_t bsm[8 * 256 * 8];   // [q=k/8][col][8] bf16 = 32 KB
    const int bid = blockIdx.x;
    const int rowblk = bid >> 1;
    const int col0 = (bid & 1) << 8;
    const int tid = threadIdx.x;

    {
        const int col = tid;  // 0..255
        const float* src = We + (size_t)(col0 + col) * 64;
        #pragma unroll
        for (int q = 0; q < 8; ++q) {
            float4 f0 = *(const float4*)(src + q * 8);
            float4 f1 = *(const float4*)(src + q * 8 + 4);
            *(bf16x8*)&bsm[(q * 256 + col) * 8] = cvt8(f0, f1);
        }
    }
    __syncthreads();

    const int l = tid & 63, w = tid >> 6;
    const int lo = l & 15, hi = l >> 4;
    const int rowbase = rowblk * 64 + w * 16;
    const int row_a = rowbase + lo;
    const int seq = row_a & (NSEQ - 1);
    const int t = row_a >> 10;
    const float* xrow = x + ((size_t)seq * SLEN + t) * 64;

    bf16x8 a0, a1;
    {
        const float* p = xrow + hi * 8;
        a0 = cvt8(*(const float4*)p, *(const float4*)(p + 4));
        p = xrow + 32 + hi * 8;
        a1 = cvt8(*(const float4*)p, *(const float4*)(p + 4));
    }

    #pragma unroll
    for (int nf = 0; nf < 16; ++nf) {
        f32x4 acc = {0.f, 0.f, 0.f, 0.f};
        bf16x8 b0 = *(const bf16x8*)&bsm[((0 * 4 + hi) * 256 + nf * 16 + lo) * 8];
        bf16x8 b1 = *(const bf16x8*)&bsm[((1 * 4 + hi) * 256 + nf * 16 + lo) * 8];
        acc = __builtin_amdgcn_mfma_f32_16x16x32_bf16(a0, b0, acc, 0, 0, 0);
        acc = __builtin_amdgcn_mfma_f32_16x16x32_bf16(a1, b1, acc, 0, 0, 0);
        const int col = col0 + nf * 16 + lo;
        const float bias = be[col];
        #pragma unroll
        for (int r = 0; r < 4; ++r) {
            const int rr = rowbase + hi * 4 + r;
            emb[(size_t)rr * HID + col] = (bf16_t)(acc[r] + bias);
        }
    }
}

// ---------------------------------------------------------------------------
// Persistent masked-LSTM. 256 blocks x 512 threads, 128 KB LDS, 1 block/CU.
// Group m = bid&7 (32 blocks, XCD-local with round-robin dispatch; verified
// at runtime via HW_REG_XCC_ID). Fast path: h exchanged via L1-bypass (sc0)
// loads through the shared per-XCD L2 — no per-step L2 invalidate/writeback.
// Agent-scope fallback if the group spans XCDs.
// Wave = 16 seqs x 64 gate-cols (4 N-frags = i,f,g,o at 16 units); cell
// update fully lane-local; weights LDS-resident.
// NEW (R10): h-loads pipelined with counted vmcnt(12/8/4/0) — MFMA on the
// first 4 kt starts as soon as the first 4 loads land; LDS+MFMA of segment k
// overlaps L2 latency of later segments (T4). sched_barrier(0) after each
// wait per rule #18 (asm-written regs vs MFMA hoisting).
// ---------------------------------------------------------------------------
__global__ __launch_bounds__(512, 2)
void lstm_kernel(const bf16_t* __restrict__ emb, const int* __restrict__ mask,
                 const float* __restrict__ Wih, const float* __restrict__ Whh,
                 const float* __restrict__ bih, const float* __restrict__ bhh,
                 const float* __restrict__ h0, const float* __restrict__ c0,
                 bf16_t* __restrict__ hbuf,        // [2][1024][512] bf16
                 unsigned int* __restrict__ cnt,   // [0..511] counters, [512..519] xcd masks
                 float* __restrict__ out)
{
    extern __shared__ bf16_t wsm[];   // [q=k/8 (128)][col (64)][8] = 128 KB
    const int bid = blockIdx.x;
    const int m = bid & 7;            // group (XCD-local with round-robin dispatch)
    const int jsl = bid >> 3;         // 0..31
    const int jbase = jsl * 16;       // 16 hidden units per block
    const int tid = threadIdx.x;

    // publish this block's XCD id into the group's mask (before init arrival)
    unsigned xcc = 0;
    asm volatile("s_getreg_b32 %0, hwreg(HW_REG_XCC_ID)" : "=s"(xcc));
    if (tid == 0)
        __hip_atomic_fetch_or(&cnt[512 + m], 1u << (xcc & 31u),
                              __ATOMIC_RELAXED, __HIP_MEMORY_SCOPE_AGENT);

    // ---- stage weight slice: wsm[q][col][e] = Wcat[G(col)][q*8+e] ----
    {
        const int col = tid & 63;
        const int qg = tid >> 6;          // 0..7
        const int grp = col >> 4;
        const int jj = col & 15;
        const int G = grp * 512 + jbase + jj;
        #pragma unroll
        for (int i = 0; i < 16; ++i) {
            const int q = qg * 16 + i;    // 0..127
            const int k0 = q * 8;
            const float* src = (k0 < 512) ? (Wih + (size_t)G * 512 + k0)
                                          : (Whh + (size_t)G * 512 + (k0 - 512));
            float4 f0 = *(const float4*)src;
            float4 f1 = *(const float4*)(src + 4);
            *(bf16x8*)&wsm[(q * 64 + col) * 8] = cvt8(f0, f1);
        }
    }

    const int lane = tid & 63, w = tid >> 6;
    const int lo = lane & 15, hi = lane >> 4;
    const int seqbase = m * 128 + w * 16;
    const int jg = jbase + lo;
    const int seq_a = seqbase + lo;       // this lane's A row
    const int koff = hi * 8;

    float bs[4];
    #pragma unroll
    for (int g = 0; g < 4; ++g) bs[g] = bih[g * 512 + jg] + bhh[g * 512 + jg];

    // init c and h(0) = mask0 ? emb0 : h0
    float c_reg[4];
    const float c0v = c0[jg], h0v = h0[jg];
    #pragma unroll
    for (int r = 0; r < 4; ++r) {
        const int seq = seqbase + hi * 4 + r;
        c_reg[r] = c0v;
        const int mb0 = mask[(size_t)seq * SLEN + 0];
        const float e0 = (float)emb[(size_t)seq * HID + jg];
        hbuf[(size_t)seq * HID + jg] = (bf16_t)(mb0 ? e0 : h0v);
    }
    __syncthreads();
    if (tid == 0)
        __hip_atomic_fetch_add(&cnt[m * 64], 1u, __ATOMIC_RELEASE,
                               __HIP_MEMORY_SCOPE_AGENT);

    bool fast = false;

    for (int t = 0; t < SLEN; ++t) {
        // ---- prefetch (h-independent) before the barrier: mask + emb frags ----
        const int mb = mask[(size_t)seq_a * SLEN + t];
        const bf16_t* erow = emb + ((size_t)t * NSEQ + seq_a) * HID + koff;
        bf16x8 ex[16];
        #pragma unroll
        for (int kt = 0; kt < 16; ++kt)
            ex[kt] = *(const bf16x8*)(erow + kt * 32);

        // ---- group barrier ----
        if (tid == 0) {
            const unsigned target = 32u * (unsigned)(t + 1);
            unsigned it = 0;
            while (__hip_atomic_load(&cnt[m * 64], __ATOMIC_RELAXED,
                                     __HIP_MEMORY_SCOPE_AGENT) < target &&
                   ++it < (1u << 27)) {
                __builtin_amdgcn_s_sleep(1);
            }
            if (!fast)   // slow path: agent acquire (L2 invalidate)
                (void)__hip_atomic_load(&cnt[m * 64], __ATOMIC_ACQUIRE,
                                        __HIP_MEMORY_SCOPE_AGENT);
        }
        __syncthreads();
        if (t == 0) {
            const unsigned gm = __hip_atomic_load(&cnt[512 + m], __ATOMIC_RELAXED,
                                                  __HIP_MEMORY_SCOPE_AGENT);
            fast = (__popc(gm) == 1);   // uniform across block
        }

        const bf16_t* hb_r = hbuf + (size_t)(t & 1) * (NSEQ * HID);
        bf16_t* hb_w = hbuf + (size_t)((t + 1) & 1) * (NSEQ * HID);
        const unsigned long long hrow =
            (unsigned long long)(hb_r + (size_t)seq_a * HID + koff);

        // ---- h loads: issue all 16 (sc0, L1-bypass), consume in 4-kt
        //      segments gated by counted vmcnt (pipelined, T4) ----
        union HU { u32x4 u; bf16x8 h; };
        HU h_[16];
        #define HL(i, OFF) \
            asm volatile("global_load_dwordx4 %0, %1, off offset:" OFF " sc0" \
                         : "=v"(h_[i].u) : "v"(hrow));
        HL(0, "0")    HL(1, "64")   HL(2, "128")  HL(3, "192")
        HL(4, "256")  HL(5, "320")  HL(6, "384")  HL(7, "448")
        HL(8, "512")  HL(9, "576")  HL(10, "640") HL(11, "704")
        HL(12, "768") HL(13, "832") HL(14, "896") HL(15, "960")
        #undef HL

        f32x4 acc[4];
        #pragma unroll
        for (int nf = 0; nf < 4; ++nf) acc[nf] = (f32x4){0.f, 0.f, 0.f, 0.f};

        // fused per-kt body: x-half (select) at kqL=kt*4+hi, h-half at
        // kqH=(kt+16)*4+hi — both consume h_[kt].
        #define KT_SEG(K0)                                                         \
            _Pragma("unroll")                                                      \
            for (int kt = K0; kt < K0 + 4; ++kt) {                                 \
                const bf16x8 a = mb ? ex[kt] : h_[kt].h;                           \
                _Pragma("unroll")                                                  \
                for (int nf = 0; nf < 4; ++nf) {                                   \
                    const bf16x8 b = *(const bf16x8*)                              \
                        &wsm[((kt * 4 + hi) * 64 + nf * 16 + lo) * 8];             \
                    acc[nf] = __builtin_amdgcn_mfma_f32_16x16x32_bf16(a, b, acc[nf], 0, 0, 0); \
                }                                                                  \
                _Pragma("unroll")                                                  \
                for (int nf = 0; nf < 4; ++nf) {                                   \
                    const bf16x8 b = *(const bf16x8*)                              \
                        &wsm[(((kt + 16) * 4 + hi) * 64 + nf * 16 + lo) * 8];      \
                    acc[nf] = __builtin_amdgcn_mfma_f32_16x16x32_bf16(h_[kt].h, b, acc[nf], 0, 0, 0); \
                }                                                                  \
            }

        asm volatile("s_waitcnt vmcnt(12)" ::: "memory");
        __builtin_amdgcn_sched_barrier(0);
        KT_SEG(0)
        asm volatile("s_waitcnt vmcnt(8)" ::: "memory");
        __builtin_amdgcn_sched_barrier(0);
        KT_SEG(4)
        asm volatile("s_waitcnt vmcnt(4)" ::: "memory");
        __builtin_amdgcn_sched_barrier(0);
        KT_SEG(8)
        asm volatile("s_waitcnt vmcnt(0)" ::: "memory");
        __builtin_amdgcn_sched_barrier(0);
        KT_SEG(12)
        #undef KT_SEG

        // ---- lane-local LSTM cell update (acc[0..3] = i,f,g,o at unit jg) ----
        #pragma unroll
        for (int r = 0; r < 4; ++r) {
            const float iv = acc[0][r] + bs[0];
            const float fv = acc[1][r] + bs[1];
            const float gv = acc[2][r] + bs[2];
            const float ov = acc[3][r] + bs[3];
            const float cn = sigf(fv) * c_reg[r] + sigf(iv) * tanh_(gv);
            c_reg[r] = cn;
            const float hv = sigf(ov) * tanh_(cn);
            const int s = seqbase + hi * 4 + r;
            hb_w[(size_t)s * HID + jg] = (bf16_t)hv;
            if (t == SLEN - 1) out[(size_t)s * HID + jg] = hv;
        }
        __syncthreads();   // drains h stores (vmcnt 0) before the counter bump
        if (tid == 0) {
            if (fast)
                __hip_atomic_fetch_add(&cnt[m * 64], 1u, __ATOMIC_RELAXED,
                                       __HIP_MEMORY_SCOPE_AGENT);
            else
                __hip_atomic_fetch_add(&cnt[m * 64], 1u, __ATOMIC_RELEASE,
                                       __HIP_MEMORY_SCOPE_AGENT);
        }
    }
}

// ---------------------------------------------------------------------------
extern "C" void kernel_launch(void* const* d_in, const int* in_sizes, int n_in,
                              void* d_out, int out_size, void* d_ws, size_t ws_size,
                              hipStream_t stream)
{
    const float* x    = (const float*)d_in[0];
    const int*   mask = (const int*)d_in[1];
    const float* We   = (const float*)d_in[2];
    const float* be   = (const float*)d_in[3];
    const float* Wih  = (const float*)d_in[4];
    const float* Whh  = (const float*)d_in[5];
    const float* bih  = (const float*)d_in[6];
    const float* bhh  = (const float*)d_in[7];
    const float* h0   = (const float*)d_in[8];
    const float* c0   = (const float*)d_in[9];
    float* out = (float*)d_out;

    unsigned char* ws = (unsigned char*)d_ws;
    unsigned int* cnt = (unsigned int*)ws;                       // 4 KB
    bf16_t* hbuf = (bf16_t*)(ws + 4096);                         // 2 MB
    bf16_t* emb  = (bf16_t*)(ws + 4096 + (size_t)2 * NSEQ * HID * 2);  // ~100 MB

    hipMemsetAsync(cnt, 0, 4096, stream);

    embed_kernel<<<3200, 256, 0, stream>>>(x, We, be, emb);

    hipFuncSetAttribute(reinterpret_cast<const void*>(lstm_kernel),
                        hipFuncAttributeMaxDynamicSharedMemorySize, 131072);
    lstm_kernel<<<256, 512, 131072, stream>>>(emb, mask, Wih, Whh, bih, bhh,
                                              h0, c0, hbuf, cnt, out);
}